// Round 1
// baseline (303.324 us; speedup 1.0000x reference)
//
#include <hip/hip_runtime.h>
#include <stdint.h>

#define NTOK 16384   // B*S = 4*4096
#define DIN 512
#define DOUT 512
#define KE 8
#define BM 128
#define BN 128
#define BK 64

typedef unsigned short u16;
typedef u16 u16x8 __attribute__((ext_vector_type(8)));
typedef __bf16 bf16x8 __attribute__((ext_vector_type(8)));
typedef float f32x4 __attribute__((ext_vector_type(4)));

__device__ __forceinline__ u16 f2bf(float f) {
  union { float f; unsigned u; } v; v.f = f;
  unsigned r = v.u + 0x7FFFu + ((v.u >> 16) & 1u);   // RNE; inputs are finite
  return (u16)(r >> 16);
}

// async global->LDS, 16B per lane; LDS dest is wave-uniform base + lane*16
#define GLOAD_LDS16(gp, lp)                                              \
  __builtin_amdgcn_global_load_lds(                                     \
      (__attribute__((address_space(1))) void*)(gp),                    \
      (__attribute__((address_space(3))) void*)(lp), 16, 0, 0)

// ---------------------------------------------------------------------------
// Kernel 1: gating (softmax over 8 experts) + x fp32->bf16 cast, fused.
// 1 wave per token (4 tokens/wave sequentially), 16 tokens/block.
// ---------------------------------------------------------------------------
__global__ __launch_bounds__(256) void gate_conv_kernel(
    const float* __restrict__ x, const float* __restrict__ mw,
    const float* __restrict__ mb, u16* __restrict__ xbf,
    float* __restrict__ coeffs) {
  __shared__ __align__(16) float mwS[KE * DIN];   // 16 KB
  const int tid = threadIdx.x;
  const int wave = tid >> 6, lane = tid & 63;

#pragma unroll
  for (int i = 0; i < 4; ++i) {
    const int idx = (tid + i * 256) * 4;
    *(float4*)&mwS[idx] = *(const float4*)&mw[idx];
  }
  float mbr[KE];
#pragma unroll
  for (int k = 0; k < KE; ++k) mbr[k] = mb[k];
  __syncthreads();

#pragma unroll
  for (int t = 0; t < 4; ++t) {
    const int tok = blockIdx.x * 16 + wave * 4 + t;
    const float* xr = x + (size_t)tok * DIN + lane * 8;
    const float4 xa = *(const float4*)xr;
    const float4 xb = *(const float4*)(xr + 4);

    u16x8 p;
    p[0] = f2bf(xa.x); p[1] = f2bf(xa.y); p[2] = f2bf(xa.z); p[3] = f2bf(xa.w);
    p[4] = f2bf(xb.x); p[5] = f2bf(xb.y); p[6] = f2bf(xb.z); p[7] = f2bf(xb.w);
    *(u16x8*)(xbf + (size_t)tok * DIN + lane * 8) = p;

    float lg[KE];
#pragma unroll
    for (int k = 0; k < KE; ++k) {
      const float* wr = &mwS[k * DIN + lane * 8];
      const float4 w0 = *(const float4*)wr;
      const float4 w1 = *(const float4*)(wr + 4);
      lg[k] = xa.x * w0.x + xa.y * w0.y + xa.z * w0.z + xa.w * w0.w +
              xb.x * w1.x + xb.y * w1.y + xb.z * w1.z + xb.w * w1.w;
    }
#pragma unroll
    for (int off = 32; off; off >>= 1)
#pragma unroll
      for (int k = 0; k < KE; ++k) lg[k] += __shfl_xor(lg[k], off);

#pragma unroll
    for (int k = 0; k < KE; ++k) lg[k] += mbr[k];
    float mx = lg[0];
#pragma unroll
    for (int k = 1; k < KE; ++k) mx = fmaxf(mx, lg[k]);
    float s = 0.f;
#pragma unroll
    for (int k = 0; k < KE; ++k) { lg[k] = __expf(lg[k] - mx); s += lg[k]; }
    const float inv = 1.f / s;
    if (lane == 0) {
      float* cp = coeffs + (size_t)tok * KE;
      float4 c0, c1;
      c0.x = lg[0] * inv; c0.y = lg[1] * inv; c0.z = lg[2] * inv; c0.w = lg[3] * inv;
      c1.x = lg[4] * inv; c1.y = lg[5] * inv; c1.z = lg[6] * inv; c1.w = lg[7] * inv;
      *(float4*)cp = c0;
      *(float4*)(cp + 4) = c1;
    }
  }
}

// ---------------------------------------------------------------------------
// Kernel 2: expert weights fp32 -> bf16 cast. 8 elements/thread.
// ---------------------------------------------------------------------------
__global__ __launch_bounds__(256) void wconv_kernel(
    const float* __restrict__ w, u16* __restrict__ wbf) {
  const size_t i = ((size_t)blockIdx.x * 256 + threadIdx.x) * 8;
  const float4 a = *(const float4*)&w[i];
  const float4 b = *(const float4*)&w[i + 4];
  u16x8 p;
  p[0] = f2bf(a.x); p[1] = f2bf(a.y); p[2] = f2bf(a.z); p[3] = f2bf(a.w);
  p[4] = f2bf(b.x); p[5] = f2bf(b.y); p[6] = f2bf(b.z); p[7] = f2bf(b.w);
  *(u16x8*)&wbf[i] = p;
}

// ---------------------------------------------------------------------------
// Kernel 3: main MoE GEMM. y[m,o] = sum_e c[m,e] * (sum_i x[m,i] W_e[o,i])
//                                  + sum_e c[m,e] * beta[e,o]
// m97-structure: 128x128 tile, 4 waves, 4x4 frags of 16x16x32 bf16 MFMA,
// BK=64, global_load_lds width-16 staging, per-expert partial acc rescaled
// in fp32 at each 512-reduction boundary.
// ---------------------------------------------------------------------------
__global__ __launch_bounds__(256, 2) void moe_gemm_kernel(
    const u16* __restrict__ xbf, const u16* __restrict__ wbf,
    const float* __restrict__ coeffs, const float* __restrict__ ebias,
    float* __restrict__ out) {
  __shared__ __align__(16) u16 As[BM * BK];     // [m][k], row stride 64 el
  __shared__ __align__(16) u16 Bs[BN * BK];     // [o][k]
  __shared__ __align__(16) float Cs[BM * KE];   // coeffs tile
  __shared__ __align__(16) float BiS[KE * BN];  // bias tile [e][o]

  const int tid = threadIdx.x;
  const int wave = tid >> 6, lane = tid & 63;
  const int m0 = blockIdx.y * BM;
  const int n0 = blockIdx.x * BN;
  const int wm = (wave >> 1) * 64;   // wave's row offset in tile
  const int wn = (wave & 1) * 64;    // wave's col offset in tile

  // stage coeffs (128x8 fp32) and bias (8x128 fp32): one float4 per thread
  ((float4*)Cs)[tid] = ((const float4*)(coeffs + (size_t)m0 * KE))[tid];
  {
    const int k = tid >> 5, c = (tid & 31) * 4;
    *(float4*)&BiS[k * BN + c] = *(const float4*)&ebias[k * DOUT + n0 + c];
  }

  // staging source mapping: chunk ci = wave*4+j covers tile rows ci*8..ci*8+7;
  // lane covers row ci*8 + (lane>>3), cols (lane&7)*8 .. +8  (16 B)
  const int srow = wave * 32 + (lane >> 3);
  const int scol = (lane & 7) * 8;
  const u16* aBase = xbf + (size_t)(m0 + srow) * DIN + scol;

  f32x4 acc[4][4] = {};

  for (int e = 0; e < KE; ++e) {
    f32x4 part[4][4] = {};
    const u16* bBase =
        wbf + (size_t)e * DOUT * DIN + (size_t)(n0 + srow) * DIN + scol;

    for (int t = 0; t < DIN / BK; ++t) {   // 8 BK-tiles per expert
      const int i0 = t * BK;
      __syncthreads();   // prior tile's LDS reads done
#pragma unroll
      for (int j = 0; j < 4; ++j) {
        GLOAD_LDS16(aBase + (size_t)(j * 8) * DIN + i0, &As[(wave * 4 + j) * 512]);
        GLOAD_LDS16(bBase + (size_t)(j * 8) * DIN + i0, &Bs[(wave * 4 + j) * 512]);
      }
      __syncthreads();   // barrier drains vmcnt -> LDS valid
#pragma unroll
      for (int ks = 0; ks < 2; ++ks) {
        bf16x8 af[4], bfv[4];
#pragma unroll
        for (int mi = 0; mi < 4; ++mi)
          af[mi] = *(const bf16x8*)&As[(wm + mi * 16 + (lane & 15)) * BK +
                                       ks * 32 + (lane >> 4) * 8];
#pragma unroll
        for (int ni = 0; ni < 4; ++ni)
          bfv[ni] = *(const bf16x8*)&Bs[(wn + ni * 16 + (lane & 15)) * BK +
                                        ks * 32 + (lane >> 4) * 8];
#pragma unroll
        for (int mi = 0; mi < 4; ++mi)
#pragma unroll
          for (int ni = 0; ni < 4; ++ni)
            part[mi][ni] = __builtin_amdgcn_mfma_f32_16x16x32_bf16(
                af[mi], bfv[ni], part[mi][ni], 0, 0, 0);
      }
    }

    // fold expert partial into final acc, scaled by c[row, e] (fp32)
    // C/D layout (verified m89/m91): col = lane&15, row = (lane>>4)*4 + reg
#pragma unroll
    for (int mi = 0; mi < 4; ++mi) {
      const int rb = wm + mi * 16 + (lane >> 4) * 4;
#pragma unroll
      for (int j = 0; j < 4; ++j) {
        const float cf = Cs[(rb + j) * KE + e];
#pragma unroll
        for (int ni = 0; ni < 4; ++ni) acc[mi][ni][j] += cf * part[mi][ni][j];
      }
    }
  }

  // epilogue: rank-8 bias update + store
  float bcol[4][KE];
#pragma unroll
  for (int ni = 0; ni < 4; ++ni) {
    const int col = wn + ni * 16 + (lane & 15);
#pragma unroll
    for (int k = 0; k < KE; ++k) bcol[ni][k] = BiS[k * BN + col];
  }
#pragma unroll
  for (int mi = 0; mi < 4; ++mi) {
    const int rb = wm + mi * 16 + (lane >> 4) * 4;
#pragma unroll
    for (int j = 0; j < 4; ++j) {
      const int row = rb + j;
      float cr[KE];
#pragma unroll
      for (int k = 0; k < KE; ++k) cr[k] = Cs[row * KE + k];
#pragma unroll
      for (int ni = 0; ni < 4; ++ni) {
        float bias = 0.f;
#pragma unroll
        for (int k = 0; k < KE; ++k) bias += cr[k] * bcol[ni][k];
        const int col = wn + ni * 16 + (lane & 15);
        out[(size_t)(m0 + row) * DOUT + n0 + col] = acc[mi][ni][j] + bias;
      }
    }
  }
}

// ---------------------------------------------------------------------------
extern "C" void kernel_launch(void* const* d_in, const int* in_sizes, int n_in,
                              void* d_out, int out_size, void* d_ws,
                              size_t ws_size, hipStream_t stream) {
  (void)in_sizes; (void)n_in; (void)out_size; (void)ws_size;
  const float* x  = (const float*)d_in[0];   // [4,4096,512]
  const float* ew = (const float*)d_in[1];   // [8,512,512]
  const float* eb = (const float*)d_in[2];   // [8,512]
  const float* mw = (const float*)d_in[3];   // [8,512]
  const float* mb = (const float*)d_in[4];   // [8]
  float* out = (float*)d_out;                // [4,4096,512]

  // workspace layout: xbf 16 MB | wbf 4 MB | coeffs 0.5 MB  (~20.5 MB)
  u16* xbf = (u16*)d_ws;
  u16* wbf = (u16*)((char*)d_ws + (size_t)NTOK * DIN * 2);
  float* coeffs =
      (float*)((char*)d_ws + (size_t)NTOK * DIN * 2 + (size_t)KE * DOUT * DIN * 2);

  hipLaunchKernelGGL(gate_conv_kernel, dim3(NTOK / 16), dim3(256), 0, stream,
                     x, mw, mb, xbf, coeffs);
  hipLaunchKernelGGL(wconv_kernel, dim3(KE * DOUT * DIN / (256 * 8)), dim3(256),
                     0, stream, ew, wbf);
  hipLaunchKernelGGL(moe_gemm_kernel, dim3(DOUT / BN, NTOK / BM), dim3(256), 0,
                     stream, xbf, wbf, coeffs, eb, out);
}

// Round 2
// 215.658 us; speedup vs baseline: 1.4065x; 1.4065x over previous
//
#include <hip/hip_runtime.h>
#include <stdint.h>

#define NTOK 16384   // B*S = 4*4096
#define DIN 512
#define DOUT 512
#define KE 8
#define BM 64
#define BN 128
#define BK 64

typedef unsigned short u16;
typedef u16 u16x8 __attribute__((ext_vector_type(8)));
typedef __bf16 bf16x8 __attribute__((ext_vector_type(8)));
typedef float f32x4 __attribute__((ext_vector_type(4)));

__device__ __forceinline__ u16 f2bf(float f) {
  union { float f; unsigned u; } v; v.f = f;
  unsigned r = v.u + 0x7FFFu + ((v.u >> 16) & 1u);   // RNE; inputs are finite
  return (u16)(r >> 16);
}

// async global->LDS, 16B per lane; LDS dest is wave-uniform base + lane*16
#define GLOAD_LDS16(gp, lp)                                              \
  __builtin_amdgcn_global_load_lds(                                     \
      (__attribute__((address_space(1))) void*)(gp),                    \
      (__attribute__((address_space(3))) void*)(lp), 16, 0, 0)

// ---------------------------------------------------------------------------
// Kernel 1: gating (softmax over 8 experts) + x fp32->bf16 cast, fused.
// ---------------------------------------------------------------------------
__global__ __launch_bounds__(256) void gate_conv_kernel(
    const float* __restrict__ x, const float* __restrict__ mw,
    const float* __restrict__ mb, u16* __restrict__ xbf,
    float* __restrict__ coeffs) {
  __shared__ __align__(16) float mwS[KE * DIN];   // 16 KB
  const int tid = threadIdx.x;
  const int wave = tid >> 6, lane = tid & 63;

#pragma unroll
  for (int i = 0; i < 4; ++i) {
    const int idx = (tid + i * 256) * 4;
    *(float4*)&mwS[idx] = *(const float4*)&mw[idx];
  }
  float mbr[KE];
#pragma unroll
  for (int k = 0; k < KE; ++k) mbr[k] = mb[k];
  __syncthreads();

#pragma unroll
  for (int t = 0; t < 4; ++t) {
    const int tok = blockIdx.x * 16 + wave * 4 + t;
    const float* xr = x + (size_t)tok * DIN + lane * 8;
    const float4 xa = *(const float4*)xr;
    const float4 xb = *(const float4*)(xr + 4);

    u16x8 p;
    p[0] = f2bf(xa.x); p[1] = f2bf(xa.y); p[2] = f2bf(xa.z); p[3] = f2bf(xa.w);
    p[4] = f2bf(xb.x); p[5] = f2bf(xb.y); p[6] = f2bf(xb.z); p[7] = f2bf(xb.w);
    *(u16x8*)(xbf + (size_t)tok * DIN + lane * 8) = p;

    float lg[KE];
#pragma unroll
    for (int k = 0; k < KE; ++k) {
      const float* wr = &mwS[k * DIN + lane * 8];
      const float4 w0 = *(const float4*)wr;
      const float4 w1 = *(const float4*)(wr + 4);
      lg[k] = xa.x * w0.x + xa.y * w0.y + xa.z * w0.z + xa.w * w0.w +
              xb.x * w1.x + xb.y * w1.y + xb.z * w1.z + xb.w * w1.w;
    }
#pragma unroll
    for (int off = 32; off; off >>= 1)
#pragma unroll
      for (int k = 0; k < KE; ++k) lg[k] += __shfl_xor(lg[k], off);

#pragma unroll
    for (int k = 0; k < KE; ++k) lg[k] += mbr[k];
    float mx = lg[0];
#pragma unroll
    for (int k = 1; k < KE; ++k) mx = fmaxf(mx, lg[k]);
    float s = 0.f;
#pragma unroll
    for (int k = 0; k < KE; ++k) { lg[k] = __expf(lg[k] - mx); s += lg[k]; }
    const float inv = 1.f / s;
    if (lane == 0) {
      float* cp = coeffs + (size_t)tok * KE;
      float4 c0, c1;
      c0.x = lg[0] * inv; c0.y = lg[1] * inv; c0.z = lg[2] * inv; c0.w = lg[3] * inv;
      c1.x = lg[4] * inv; c1.y = lg[5] * inv; c1.z = lg[6] * inv; c1.w = lg[7] * inv;
      *(float4*)cp = c0;
      *(float4*)(cp + 4) = c1;
    }
  }
}

// ---------------------------------------------------------------------------
// Kernel 2: expert weights fp32 -> bf16 cast. 8 elements/thread.
// ---------------------------------------------------------------------------
__global__ __launch_bounds__(256) void wconv_kernel(
    const float* __restrict__ w, u16* __restrict__ wbf) {
  const size_t i = ((size_t)blockIdx.x * 256 + threadIdx.x) * 8;
  const float4 a = *(const float4*)&w[i];
  const float4 b = *(const float4*)&w[i + 4];
  u16x8 p;
  p[0] = f2bf(a.x); p[1] = f2bf(a.y); p[2] = f2bf(a.z); p[3] = f2bf(a.w);
  p[4] = f2bf(b.x); p[5] = f2bf(b.y); p[6] = f2bf(b.z); p[7] = f2bf(b.w);
  *(u16x8*)&wbf[i] = p;
}

// ---------------------------------------------------------------------------
// Kernel 3: main MoE GEMM, BM=64 BN=128 BK=64, 4 blocks/CU.
// XCD-swizzled grid: XCD (b&7) owns m-blocks [x*32, x*32+32) so the 8x
// expert re-reads of the A-tile and the active B_e slice stay in per-XCD L2.
// Wave owns 32x64 of the tile: 2x4 frags of 16x16x32 bf16 MFMA.
// ---------------------------------------------------------------------------
__global__ __launch_bounds__(256, 4) void moe_gemm_kernel(
    const u16* __restrict__ xbf, const u16* __restrict__ wbf,
    const float* __restrict__ coeffs, const float* __restrict__ ebias,
    float* __restrict__ out) {
  __shared__ __align__(16) u16 As[BM * BK];     // 8 KB  [m][k]
  __shared__ __align__(16) u16 Bs[BN * BK];     // 16 KB [o][k]
  __shared__ __align__(16) float Cs[BM * KE];   // 2 KB coeffs tile
  __shared__ __align__(16) float BiS[KE * BN];  // 4 KB bias tile [e][o]

  const int tid = threadIdx.x;
  const int wave = tid >> 6, lane = tid & 63;

  // XCD swizzle: b&7 = xcd (round-robin dispatch), s = intra-XCD sequence.
  // m_blk = xcd*32 + (s&31), n_blk = s>>5  -> per-XCD A set = 2 MB (L2-fits)
  const int b = blockIdx.x;
  const int xcd = b & 7, s = b >> 3;
  const int m0 = (xcd * 32 + (s & 31)) * BM;
  const int n0 = (s >> 5) * BN;

  const int wm = (wave >> 1) * 32;   // wave's row offset: {0,32}
  const int wn = (wave & 1) * 64;    // wave's col offset: {0,64}

  // stage coeffs (64x8 fp32, threads 0-127) and bias (8x128 fp32)
  if (tid < 128) ((float4*)Cs)[tid] = ((const float4*)(coeffs + (size_t)m0 * KE))[tid];
  {
    const int k = tid >> 5, c = (tid & 31) * 4;
    *(float4*)&BiS[k * BN + c] = *(const float4*)&ebias[k * DOUT + n0 + c];
  }

  // staging: each GLOAD covers 8 rows x 64 cols (1 KB). lane -> row (lane>>3),
  // col (lane&7)*8. A: 8 chunks (2/wave); B: 16 chunks (4/wave).
  const int lrow = lane >> 3;
  const int scol = (lane & 7) * 8;
  const u16* aBase = xbf + (size_t)(m0 + wave * 16 + lrow) * DIN + scol;

  f32x4 acc[2][4] = {};

  for (int e = 0; e < KE; ++e) {
    f32x4 part[2][4] = {};
    const u16* bBase = wbf + (size_t)e * DOUT * DIN +
                       (size_t)(n0 + wave * 32 + lrow) * DIN + scol;

    for (int t = 0; t < DIN / BK; ++t) {   // 8 BK-tiles per expert
      const int i0 = t * BK;
      __syncthreads();   // prior tile's LDS reads done
#pragma unroll
      for (int j = 0; j < 2; ++j)
        GLOAD_LDS16(aBase + (size_t)(j * 8) * DIN + i0, &As[(wave * 2 + j) * 512]);
#pragma unroll
      for (int j = 0; j < 4; ++j)
        GLOAD_LDS16(bBase + (size_t)(j * 8) * DIN + i0, &Bs[(wave * 4 + j) * 512]);
      __syncthreads();   // barrier drains vmcnt -> LDS valid
#pragma unroll
      for (int ks = 0; ks < 2; ++ks) {
        bf16x8 af[2], bfv[4];
#pragma unroll
        for (int mi = 0; mi < 2; ++mi)
          af[mi] = *(const bf16x8*)&As[(wm + mi * 16 + (lane & 15)) * BK +
                                       ks * 32 + (lane >> 4) * 8];
#pragma unroll
        for (int ni = 0; ni < 4; ++ni)
          bfv[ni] = *(const bf16x8*)&Bs[(wn + ni * 16 + (lane & 15)) * BK +
                                        ks * 32 + (lane >> 4) * 8];
#pragma unroll
        for (int mi = 0; mi < 2; ++mi)
#pragma unroll
          for (int ni = 0; ni < 4; ++ni)
            part[mi][ni] = __builtin_amdgcn_mfma_f32_16x16x32_bf16(
                af[mi], bfv[ni], part[mi][ni], 0, 0, 0);
      }
    }

    // fold expert partial into final acc, scaled by c[row, e] (fp32)
    // C/D layout (m89/m91): col = lane&15, row = (lane>>4)*4 + reg
#pragma unroll
    for (int mi = 0; mi < 2; ++mi) {
      const int rb = wm + mi * 16 + (lane >> 4) * 4;
#pragma unroll
      for (int j = 0; j < 4; ++j) {
        const float cf = Cs[(rb + j) * KE + e];
#pragma unroll
        for (int ni = 0; ni < 4; ++ni) acc[mi][ni][j] += cf * part[mi][ni][j];
      }
    }
  }

  // epilogue: rank-8 bias update + store
  float bcol[4][KE];
#pragma unroll
  for (int ni = 0; ni < 4; ++ni) {
    const int col = wn + ni * 16 + (lane & 15);
#pragma unroll
    for (int k = 0; k < KE; ++k) bcol[ni][k] = BiS[k * BN + col];
  }
#pragma unroll
  for (int mi = 0; mi < 2; ++mi) {
    const int rb = wm + mi * 16 + (lane >> 4) * 4;
#pragma unroll
    for (int j = 0; j < 4; ++j) {
      const int row = rb + j;
      float cr[KE];
#pragma unroll
      for (int k = 0; k < KE; ++k) cr[k] = Cs[row * KE + k];
#pragma unroll
      for (int ni = 0; ni < 4; ++ni) {
        float bias = 0.f;
#pragma unroll
        for (int k = 0; k < KE; ++k) bias += cr[k] * bcol[ni][k];
        const int col = wn + ni * 16 + (lane & 15);
        out[(size_t)(m0 + row) * DOUT + n0 + col] = acc[mi][ni][j] + bias;
      }
    }
  }
}

// ---------------------------------------------------------------------------
extern "C" void kernel_launch(void* const* d_in, const int* in_sizes, int n_in,
                              void* d_out, int out_size, void* d_ws,
                              size_t ws_size, hipStream_t stream) {
  (void)in_sizes; (void)n_in; (void)out_size; (void)ws_size;
  const float* x  = (const float*)d_in[0];   // [4,4096,512]
  const float* ew = (const float*)d_in[1];   // [8,512,512]
  const float* eb = (const float*)d_in[2];   // [8,512]
  const float* mw = (const float*)d_in[3];   // [8,512]
  const float* mb = (const float*)d_in[4];   // [8]
  float* out = (float*)d_out;                // [4,4096,512]

  // workspace layout: xbf 16 MB | wbf 4 MB | coeffs 0.5 MB  (~20.5 MB)
  u16* xbf = (u16*)d_ws;
  u16* wbf = (u16*)((char*)d_ws + (size_t)NTOK * DIN * 2);
  float* coeffs =
      (float*)((char*)d_ws + (size_t)NTOK * DIN * 2 + (size_t)KE * DOUT * DIN * 2);

  hipLaunchKernelGGL(gate_conv_kernel, dim3(NTOK / 16), dim3(256), 0, stream,
                     x, mw, mb, xbf, coeffs);
  hipLaunchKernelGGL(wconv_kernel, dim3(KE * DOUT * DIN / (256 * 8)), dim3(256),
                     0, stream, ew, wbf);
  hipLaunchKernelGGL(moe_gemm_kernel, dim3((NTOK / BM) * (DOUT / BN)), dim3(256),
                     0, stream, xbf, wbf, coeffs, eb, out);
}